// Round 5
// baseline (88.766 us; speedup 1.0000x reference)
//
#include <hip/hip_runtime.h>

// TripletLoss, N=384, D=512, fp32 in, int labels, fp32 scalar out.
// loss = sum_a sum_p sum_n relu(d(a,p)-d(a,n)+1) / num_valid (diag counts as pos)
//
// R4-round post-mortem: the rocprof top-5 exposed a 268MB workspace re-poison
// fill (~40us, 83% HBM) running EVERY iteration -> dur_us = 40 + kernel + ~8.
// So R10's kernel was ~38us, and all three prior structures (53.7 / 43.3 / 38)
// share one invariant: 384 blocks x 768KB = 295 MB of L2 traffic, delivered at
// only ~7.4 TB/s (hot-line contention: every CU requests the same 6K lines in
// near-lockstep). Compute issue model says ~5us; traffic is the wall.
//
// R12: anchor grouping. 128 blocks x 3 anchors: one pass over X per block
// computes 3 distance rows from the SAME loads -> total L2 traffic 98 MB (3x
// cut). Per-block row rotation ((b*67)%384) decorrelates the address streams.
// Per row: 2 coalesced 1KB wave-loads + 3x16 FMA + 3 interleaved shfl chains
// (xor 8/16/32 -> 8-lane coset partials in LDS). Phase 2 = proven ballot
// compaction + pair-sum, run 3x sequentially. Same per-pair math as R10
// (absmax was 0.0). One kernel, no workspace use.

#define NPTS 384
#define DIM  512
#define NT   384
#define NW   (NT / 64)        // 6 waves
#define APB  3                // anchors per block
#define NB   (NPTS / APB)     // 128 blocks

__global__ __launch_bounds__(NT) void triplet_fused(
    const float* __restrict__ X,
    const int*   __restrict__ labels,
    float*       __restrict__ out)
{
    __shared__ float s_xa[APB][DIM];              // 6 KB anchor rows
    __shared__ float s_part[APB][NPTS * 8];       // 36 KB: 8 coset partials/row
    __shared__ float s_dp[NPTS];
    __shared__ float s_dn[NPTS];
    __shared__ int   s_lab[NPTS] __attribute__((aligned(16)));
    __shared__ int   s_cp[NW], s_cn[NW];
    __shared__ float s_red[NW];
    __shared__ int   s_nv[NW];

    const int t    = threadIdx.x;
    const int b    = blockIdx.x;
    const int a0   = b * APB;
    const int lane = t & 63, w = t >> 6;

    const float4* X4 = (const float4*)X;          // row pitch 128 float4

    // ---- stage 3 anchor rows (384 float4, coalesced) + labels --------------
    {
        const int ar = t >> 7, ac = t & 127;
        ((float4*)&s_xa[ar][0])[ac] = X4[(size_t)(a0 + ar) * (DIM / 4) + ac];
        s_lab[t] = labels[t];
    }
    __syncthreads();

    // lane's fixed k-slices of the three anchors
    const float4 a0v0 = ((const float4*)&s_xa[0][0])[lane];
    const float4 a0v1 = ((const float4*)&s_xa[0][0])[lane + 64];
    const float4 a1v0 = ((const float4*)&s_xa[1][0])[lane];
    const float4 a1v1 = ((const float4*)&s_xa[1][0])[lane + 64];
    const float4 a2v0 = ((const float4*)&s_xa[2][0])[lane];
    const float4 a2v1 = ((const float4*)&s_xa[2][0])[lane + 64];
    const int lab0 = s_lab[a0], lab1 = s_lab[a0 + 1], lab2 = s_lab[a0 + 2];

    // ---- distance sweep: 64 rows/wave, rotated start per block -------------
    const int rot  = (b * 67) % NPTS;             // 67 coprime to 384
    const int base = w * 64 + rot;                // < 768
#pragma unroll 2
    for (int r = 0; r < 64; ++r) {
        int jj = base + r; if (jj >= NPTS) jj -= NPTS;
        const float4 b0 = X4[(size_t)jj * (DIM / 4) + lane];
        const float4 b1 = X4[(size_t)jj * (DIM / 4) + 64 + lane];
        float d, s0, s1, s2;
        d = a0v0.x - b0.x; s0 = d * d;
        d = a0v0.y - b0.y; s0 = fmaf(d, d, s0);
        d = a0v0.z - b0.z; s0 = fmaf(d, d, s0);
        d = a0v0.w - b0.w; s0 = fmaf(d, d, s0);
        d = a0v1.x - b1.x; s0 = fmaf(d, d, s0);
        d = a0v1.y - b1.y; s0 = fmaf(d, d, s0);
        d = a0v1.z - b1.z; s0 = fmaf(d, d, s0);
        d = a0v1.w - b1.w; s0 = fmaf(d, d, s0);
        d = a1v0.x - b0.x; s1 = d * d;
        d = a1v0.y - b0.y; s1 = fmaf(d, d, s1);
        d = a1v0.z - b0.z; s1 = fmaf(d, d, s1);
        d = a1v0.w - b0.w; s1 = fmaf(d, d, s1);
        d = a1v1.x - b1.x; s1 = fmaf(d, d, s1);
        d = a1v1.y - b1.y; s1 = fmaf(d, d, s1);
        d = a1v1.z - b1.z; s1 = fmaf(d, d, s1);
        d = a1v1.w - b1.w; s1 = fmaf(d, d, s1);
        d = a2v0.x - b0.x; s2 = d * d;
        d = a2v0.y - b0.y; s2 = fmaf(d, d, s2);
        d = a2v0.z - b0.z; s2 = fmaf(d, d, s2);
        d = a2v0.w - b0.w; s2 = fmaf(d, d, s2);
        d = a2v1.x - b1.x; s2 = fmaf(d, d, s2);
        d = a2v1.y - b1.y; s2 = fmaf(d, d, s2);
        d = a2v1.z - b1.z; s2 = fmaf(d, d, s2);
        d = a2v1.w - b1.w; s2 = fmaf(d, d, s2);
        // three independent 3-level butterflies, interleaved for ILP
        s0 += __shfl_xor(s0,  8, 64);
        s1 += __shfl_xor(s1,  8, 64);
        s2 += __shfl_xor(s2,  8, 64);
        s0 += __shfl_xor(s0, 16, 64);
        s1 += __shfl_xor(s1, 16, 64);
        s2 += __shfl_xor(s2, 16, 64);
        s0 += __shfl_xor(s0, 32, 64);
        s1 += __shfl_xor(s1, 32, 64);
        s2 += __shfl_xor(s2, 32, 64);
        if (lane < 8) {
            s_part[0][jj * 8 + lane] = s0;
            s_part[1][jj * 8 + lane] = s1;
            s_part[2][jj * 8 + lane] = s2;
        }
    }
    __syncthreads();

    // ---- phase 2: per-anchor compaction + pair sum (proven), 3x ------------
    const unsigned long long blw = (1ull << lane) - 1ull;   // lane<64, safe
    float local = 0.f;
#pragma unroll 1
    for (int g = 0; g < APB; ++g) {
        const float* sp = &s_part[g][0];
        const float4 q0 = *(const float4*)&sp[t * 8];
        const float4 q1 = *(const float4*)&sp[t * 8 + 4];
        // row a0+g reads identical anchor data -> partials exactly 0 -> dv=0
        const float dv = sqrtf(((q0.x + q0.y) + (q0.z + q0.w)) +
                               ((q1.x + q1.y) + (q1.z + q1.w)));
        const int  lab_a = (g == 0) ? lab0 : (g == 1) ? lab1 : lab2;
        const bool isp   = (s_lab[t] == lab_a);   // diag counts as pos
        const unsigned long long m = __ballot(isp);
        __syncthreads();                          // prev iter s_dp/s_dn reads done
        if (lane == 0) { s_cp[w] = __popcll(m); s_cn[w] = 64 - __popcll(m); }
        __syncthreads();

        int basep = 0, basen = 0, np = 0, nn = 0;
#pragma unroll
        for (int i = 0; i < NW; ++i) {
            if (i < w) { basep += s_cp[i]; basen += s_cn[i]; }
            np += s_cp[i]; nn += s_cn[i];
        }
        if (isp) s_dp[basep + __popcll(m  & blw)] = dv;
        else     s_dn[basen + __popcll(~m & blw)] = dv;
        __syncthreads();

        const bool  va  = (t < nn);
        const float dna = va ? s_dn[t] : 0.f;
        for (int p = 0; p < np; ++p) {
            const float c = s_dp[p] + 1.0f;       // MARGIN
            if (va) local += fmaxf(c - dna, 0.f);
        }
    }

    // ---- global num_valid from labels alone (identical in every block) -----
    const int myl = s_lab[t];
    int npt = 0;
    const int4* L4 = (const int4*)s_lab;
#pragma unroll 8
    for (int j4 = 0; j4 < NPTS / 4; ++j4) {
        const int4 l = L4[j4];                    // broadcast read
        npt += (l.x == myl) + (l.y == myl) + (l.z == myl) + (l.w == myl);
    }
    int nvl = npt * (NPTS - npt);

    // ---- block reduce + atomic finish --------------------------------------
    for (int off = 32; off; off >>= 1) {
        local += __shfl_down(local, off, 64);
        nvl   += __shfl_down(nvl,   off, 64);
    }
    if (lane == 0) { s_red[w] = local; s_nv[w] = nvl; }
    __syncthreads();
    if (t == 0) {
        float bs = 0.f; int nv = 0;
#pragma unroll
        for (int i = 0; i < NW; ++i) { bs += s_red[i]; nv += s_nv[i]; }
        // out is memset to 0 by the harness before each verified launch
        atomicAdd(out, (float)((double)bs / ((double)nv + 1e-16)));
    }
}

extern "C" void kernel_launch(void* const* d_in, const int* in_sizes, int n_in,
                              void* d_out, int out_size, void* d_ws, size_t ws_size,
                              hipStream_t stream) {
    (void)in_sizes; (void)n_in; (void)out_size; (void)d_ws; (void)ws_size;
    const float* X      = (const float*)d_in[0];
    const int*   labels = (const int*)d_in[1];
    triplet_fused<<<dim3(NB), dim3(NT), 0, stream>>>(X, labels, (float*)d_out);
}